// Round 5
// baseline (352.973 us; speedup 1.0000x reference)
//
#include <hip/hip_runtime.h>

// Geometry fixed by reference: B*T = 128 batches, N = 65536 rows, 3 coords.
constexpr int N_ROWS  = 65536;
constexpr int NBATCH  = 128;
constexpr int THREADS = 256;

// Key identity: out[b,c] = sqrt(min_d ( ra[b,c] - 2*mul[b,c,d] + rb[b,d] )).
// The reference's argmin+gather+renorm equals this, so one streaming pass
// computing 15 sums per batch suffices.
//
// Fused single-kernel design (R5):
//  - grid = NBATCH * bpb blocks; block handles rows_per_chunk = N_ROWS/bpb rows.
//  - npass passes of 4 rows/thread (6 float4 loads). Default bpb=64 -> npass=1,
//    small register footprint; TLP (32 waves/CU, 8192 blocks) hides HBM latency.
//    R2-R4 lesson: do NOT force ILP via launch_bounds/sched_barrier — the
//    allocator spills (WRITE_SIZE 19-190 MB of scratch).
//  - Deterministic last-block finalize: int atomicAdd on a per-batch counter;
//    the last chunk re-reads all bpb partial vectors and reduces them in a
//    FIXED shfl-tree order (no FP atomics -> bit-deterministic).
__global__ __launch_bounds__(THREADS)
void nn_fused(const float* __restrict__ pred,
              const float* __restrict__ targ,
              float* __restrict__ out,
              int* __restrict__ counters,    // [NBATCH], zeroed each launch
              float* __restrict__ partial,   // [NBATCH*bpb*15]
              int bpbShift, int npass) {
    const int bpb   = 1 << bpbShift;
    const int bid   = blockIdx.x;
    const int batch = bid >> bpbShift;
    const int chunk = bid & (bpb - 1);
    const int rows_per_chunk = N_ROWS >> bpbShift;
    const long base = (long)batch * (N_ROWS * 3) + (long)chunk * rows_per_chunk * 3;
    const int  tid  = threadIdx.x;

    const float4* __restrict__ p4 = reinterpret_cast<const float4*>(pred + base);
    const float4* __restrict__ t4 = reinterpret_cast<const float4*>(targ + base);

    // acc[0..2]=ra, acc[3..5]=rb, acc[6..14]=mul[c][d]
    float acc[15];
    #pragma unroll
    for (int i = 0; i < 15; ++i) acc[i] = 0.f;

    for (int pass = 0; pass < npass; ++pass) {
        const int v = (pass * THREADS + tid) * 3;   // 4 rows = 3 float4 = 48 B
        float4 a0 = p4[v + 0], a1 = p4[v + 1], a2 = p4[v + 2];
        float4 b0 = t4[v + 0], b1 = t4[v + 1], b2 = t4[v + 2];
        const float pf[12] = {a0.x,a0.y,a0.z,a0.w, a1.x,a1.y,a1.z,a1.w,
                              a2.x,a2.y,a2.z,a2.w};
        const float tf[12] = {b0.x,b0.y,b0.z,b0.w, b1.x,b1.y,b1.z,b1.w,
                              b2.x,b2.y,b2.z,b2.w};
        #pragma unroll
        for (int r = 0; r < 4; ++r) {
            const float p0 = pf[r*3+0], p1 = pf[r*3+1], p2 = pf[r*3+2];
            const float t0 = tf[r*3+0], t1 = tf[r*3+1], t2 = tf[r*3+2];
            acc[0]  = fmaf(p0,p0,acc[0]);  acc[1]  = fmaf(p1,p1,acc[1]);  acc[2]  = fmaf(p2,p2,acc[2]);
            acc[3]  = fmaf(t0,t0,acc[3]);  acc[4]  = fmaf(t1,t1,acc[4]);  acc[5]  = fmaf(t2,t2,acc[5]);
            acc[6]  = fmaf(p0,t0,acc[6]);  acc[7]  = fmaf(p0,t1,acc[7]);  acc[8]  = fmaf(p0,t2,acc[8]);
            acc[9]  = fmaf(p1,t0,acc[9]);  acc[10] = fmaf(p1,t1,acc[10]); acc[11] = fmaf(p1,t2,acc[11]);
            acc[12] = fmaf(p2,t0,acc[12]); acc[13] = fmaf(p2,t1,acc[13]); acc[14] = fmaf(p2,t2,acc[14]);
        }
    }

    // Wave butterfly reduce (fixed order -> deterministic).
    #pragma unroll
    for (int off = 32; off > 0; off >>= 1) {
        #pragma unroll
        for (int i = 0; i < 15; ++i)
            acc[i] += __shfl_down(acc[i], off, 64);
    }

    __shared__ float wsum[4][15];
    __shared__ int   lastflag;
    const int wave = tid >> 6;
    const int lane = tid & 63;
    if (lane == 0) {
        #pragma unroll
        for (int i = 0; i < 15; ++i) wsum[wave][i] = acc[i];
    }
    __syncthreads();
    if (tid < 15) {
        partial[(long)bid * 15 + tid] =
            wsum[0][tid] + wsum[1][tid] + wsum[2][tid] + wsum[3][tid];
    }
    if (tid == 0) {
        __threadfence();                              // partials visible device-wide
        const int old = atomicAdd(&counters[batch], 1);
        lastflag = (old == bpb - 1);
    }
    __syncthreads();
    if (!lastflag) return;

    // Last chunk of this batch: reduce all bpb partial vectors, fixed order.
    __threadfence();                                  // acquire others' partials
    if (tid < 64) {
        float s[15];
        if (lane < bpb) {
            const float* pp = partial + (long)(batch * bpb + lane) * 15;
            #pragma unroll
            for (int i = 0; i < 15; ++i) s[i] = pp[i];
        } else {
            #pragma unroll
            for (int i = 0; i < 15; ++i) s[i] = 0.f;
        }
        #pragma unroll
        for (int off = 32; off > 0; off >>= 1) {
            #pragma unroll
            for (int i = 0; i < 15; ++i)
                s[i] += __shfl_down(s[i], off, 64);
        }
        if (lane == 0) {
            #pragma unroll
            for (int c = 0; c < 3; ++c) {
                float m = 3.0e38f;
                #pragma unroll
                for (int d = 0; d < 3; ++d) {
                    float dist = s[c] - 2.0f * s[6 + c * 3 + d] + s[3 + d];
                    m = fminf(m, dist);
                }
                out[batch * 3 + c] = sqrtf(fmaxf(m, 0.f));
            }
        }
    }
}

extern "C" void kernel_launch(void* const* d_in, const int* in_sizes, int n_in,
                              void* d_out, int out_size, void* d_ws, size_t ws_size,
                              hipStream_t stream) {
    const float* pred = (const float*)d_in[0];
    const float* targ = (const float*)d_in[1];
    float* out = (float*)d_out;

    // ws layout: [0,512) int counters (128 used), then partials.
    int*   counters = (int*)d_ws;
    float* partial  = (float*)((char*)d_ws + 512);

    // Prefer bpb=64 (8192 blocks, 1 pass); shrink if ws is too small.
    int bpbShift = 6;
    while (bpbShift > 0 &&
           512 + (size_t)(NBATCH << bpbShift) * 15 * sizeof(float) > ws_size)
        --bpbShift;
    const int bpb   = 1 << bpbShift;
    const int npass = (N_ROWS >> bpbShift) / (THREADS * 4);

    hipMemsetAsync(counters, 0, NBATCH * sizeof(int), stream);
    nn_fused<<<NBATCH * bpb, THREADS, 0, stream>>>(pred, targ, out, counters,
                                                   partial, bpbShift, npass);
}

// Round 6
// 51.927 us; speedup vs baseline: 6.7974x; 6.7974x over previous
//
#include <hip/hip_runtime.h>

// Geometry fixed by reference: B*T = 128 batches, N = 65536 rows, 3 coords.
constexpr int N_ROWS  = 65536;
constexpr int NBATCH  = 128;
constexpr int THREADS = 128;                       // 2 waves
constexpr int ROWS_PER_PASS = THREADS * 4;         // 512 rows per block-pass
constexpr int FLT_PER_PASS  = ROWS_PER_PASS * 3;   // 1536 floats = 6 KB/input
constexpr int F4_PER_PASS   = FLT_PER_PASS / 4;    // 384 float4

// Key identity: out[b,c] = sqrt(min_d ( ra[b,c] - 2*mul[b,c,d] + rb[b,d] )).
// One streaming pass computing 15 sums per batch reproduces the reference.
//
// R5 lesson: per-block __threadfence() (device scope, cross-XCD) = 9x
// slowdown — back to two kernels, no atomics, no fences.
// R0-R4 lesson: don't fight the register allocator for ILP (it spills);
// rely on TLP.
// R6 change: the direct 48B-per-lane loads issued 3x the cache-line
// requests and thrashed L1 (18 waves x 3KB spans > 32KB), tripling L1<->L2
// traffic (~17.5us) on top of the HBM stream (~16us). Now: fully-coalesced
// unit-stride float4 loads -> LDS (linear write, conflict-free), then
// ds_read_b128 rows at 48B stride (<=2-way aliasing ~ free) -> same 15 sums.

__device__ __forceinline__ void accum12(const float4& a0, const float4& a1,
                                        const float4& a2, const float4& b0,
                                        const float4& b1, const float4& b2,
                                        float acc[15]) {
    const float pf[12] = {a0.x,a0.y,a0.z,a0.w, a1.x,a1.y,a1.z,a1.w,
                          a2.x,a2.y,a2.z,a2.w};
    const float tf[12] = {b0.x,b0.y,b0.z,b0.w, b1.x,b1.y,b1.z,b1.w,
                          b2.x,b2.y,b2.z,b2.w};
    #pragma unroll
    for (int r = 0; r < 4; ++r) {
        const float p0 = pf[r*3+0], p1 = pf[r*3+1], p2 = pf[r*3+2];
        const float t0 = tf[r*3+0], t1 = tf[r*3+1], t2 = tf[r*3+2];
        acc[0]  = fmaf(p0,p0,acc[0]);  acc[1]  = fmaf(p1,p1,acc[1]);  acc[2]  = fmaf(p2,p2,acc[2]);
        acc[3]  = fmaf(t0,t0,acc[3]);  acc[4]  = fmaf(t1,t1,acc[4]);  acc[5]  = fmaf(t2,t2,acc[5]);
        acc[6]  = fmaf(p0,t0,acc[6]);  acc[7]  = fmaf(p0,t1,acc[7]);  acc[8]  = fmaf(p0,t2,acc[8]);
        acc[9]  = fmaf(p1,t0,acc[9]);  acc[10] = fmaf(p1,t1,acc[10]); acc[11] = fmaf(p1,t2,acc[11]);
        acc[12] = fmaf(p2,t0,acc[12]); acc[13] = fmaf(p2,t1,acc[13]); acc[14] = fmaf(p2,t2,acc[14]);
    }
}

__global__ void nn_partial(const float* __restrict__ pred,
                           const float* __restrict__ targ,
                           float* __restrict__ partial,
                           int bpbShift, int npass) {
    __shared__ float A[FLT_PER_PASS];   // 6 KB pred staging
    __shared__ float B[FLT_PER_PASS];   // 6 KB targ staging
    __shared__ float wsum[2][15];

    const int bid   = blockIdx.x;
    const int batch = bid >> bpbShift;
    const int chunk = bid & ((1 << bpbShift) - 1);
    const int tid   = threadIdx.x;

    const long baseF4 = (long)batch * (N_ROWS * 3 / 4)
                      + (long)chunk * npass * F4_PER_PASS;
    const float4* __restrict__ p4 = reinterpret_cast<const float4*>(pred) + baseF4;
    const float4* __restrict__ t4 = reinterpret_cast<const float4*>(targ) + baseF4;

    float acc[15];
    #pragma unroll
    for (int i = 0; i < 15; ++i) acc[i] = 0.f;

    for (int pass = 0; pass < npass; ++pass) {
        const int pb = pass * F4_PER_PASS;
        // Fully-coalesced unit-stride loads: 3 float4 per thread per input.
        float4 pa0 = p4[pb + 0*THREADS + tid];
        float4 pa1 = p4[pb + 1*THREADS + tid];
        float4 pa2 = p4[pb + 2*THREADS + tid];
        float4 ta0 = t4[pb + 0*THREADS + tid];
        float4 ta1 = t4[pb + 1*THREADS + tid];
        float4 ta2 = t4[pb + 2*THREADS + tid];
        float4* Aw = reinterpret_cast<float4*>(A);
        float4* Bw = reinterpret_cast<float4*>(B);
        Aw[0*THREADS + tid] = pa0;  Aw[1*THREADS + tid] = pa1;  Aw[2*THREADS + tid] = pa2;
        Bw[0*THREADS + tid] = ta0;  Bw[1*THREADS + tid] = ta1;  Bw[2*THREADS + tid] = ta2;
        __syncthreads();
        // Row-aligned readback: thread t owns rows [4t,4t+4) = floats [12t,12t+12).
        // Byte offset 48t is 16B-aligned; <=2-way bank aliasing per 16-lane group.
        const float4* Ar = reinterpret_cast<const float4*>(A + 12 * tid);
        const float4* Br = reinterpret_cast<const float4*>(B + 12 * tid);
        float4 a0 = Ar[0], a1 = Ar[1], a2 = Ar[2];
        float4 b0 = Br[0], b1 = Br[1], b2 = Br[2];
        accum12(a0, a1, a2, b0, b1, b2, acc);
        __syncthreads();   // before next pass overwrites A/B
    }

    // Wave butterfly reduce (fixed order -> deterministic).
    #pragma unroll
    for (int off = 32; off > 0; off >>= 1) {
        #pragma unroll
        for (int i = 0; i < 15; ++i)
            acc[i] += __shfl_down(acc[i], off, 64);
    }
    const int wave = tid >> 6;
    const int lane = tid & 63;
    if (lane == 0) {
        #pragma unroll
        for (int i = 0; i < 15; ++i) wsum[wave][i] = acc[i];
    }
    __syncthreads();
    if (tid < 15)
        partial[(long)bid * 15 + tid] = wsum[0][tid] + wsum[1][tid];
}

// 128 blocks x 64 lanes; lane k accumulates chunks {k, k+64, ...} serially
// (fixed order), then a fixed shfl tree -> deterministic.
__global__ void nn_final(const float* __restrict__ partial,
                         float* __restrict__ out, int bpb) {
    const int b    = blockIdx.x;
    const int lane = threadIdx.x;
    float s[15];
    #pragma unroll
    for (int i = 0; i < 15; ++i) s[i] = 0.f;
    for (int k = lane; k < bpb; k += 64) {
        const float* pp = partial + (long)(b * bpb + k) * 15;
        #pragma unroll
        for (int i = 0; i < 15; ++i) s[i] += pp[i];
    }
    #pragma unroll
    for (int off = 32; off > 0; off >>= 1) {
        #pragma unroll
        for (int i = 0; i < 15; ++i)
            s[i] += __shfl_down(s[i], off, 64);
    }
    if (lane == 0) {
        #pragma unroll
        for (int c = 0; c < 3; ++c) {
            float m = 3.0e38f;
            #pragma unroll
            for (int d = 0; d < 3; ++d) {
                float dist = s[c] - 2.0f * s[6 + c * 3 + d] + s[3 + d];
                m = fminf(m, dist);
            }
            out[b * 3 + c] = sqrtf(fmaxf(m, 0.f));
        }
    }
}

extern "C" void kernel_launch(void* const* d_in, const int* in_sizes, int n_in,
                              void* d_out, int out_size, void* d_ws, size_t ws_size,
                              hipStream_t stream) {
    const float* pred = (const float*)d_in[0];
    const float* targ = (const float*)d_in[1];
    float* out     = (float*)d_out;
    float* partial = (float*)d_ws;

    // Prefer bpb=128 (16384 blocks, 1 pass each); shrink if ws too small.
    int bpbShift = 7;
    while (bpbShift > 0 &&
           (size_t)(NBATCH << bpbShift) * 15 * sizeof(float) > ws_size)
        --bpbShift;
    const int bpb   = 1 << bpbShift;
    const int npass = (N_ROWS >> bpbShift) / ROWS_PER_PASS;

    nn_partial<<<NBATCH * bpb, THREADS, 0, stream>>>(pred, targ, partial,
                                                     bpbShift, npass);
    nn_final<<<NBATCH, 64, 0, stream>>>(partial, out, bpb);
}

// Round 7
// 37.089 us; speedup vs baseline: 9.5170x; 1.4001x over previous
//
#include <hip/hip_runtime.h>

// Geometry fixed by reference: B*T = 128 batches, N = 65536 rows, 3 coords.
constexpr int N_ROWS  = 65536;
constexpr int NBATCH  = 128;
constexpr int THREADS = 256;
constexpr int BPB     = 16;                           // 2048 blocks = 8/CU
constexpr int ROWS_PER_BLOCK = N_ROWS / BPB;          // 4096
constexpr int NPASS = ROWS_PER_BLOCK / THREADS;       // 16 rows/thread

// Key identity: out[b,c] = sqrt(min_d ( ra[b,c] - 2*mul[b,c,d] + rb[b,d] )).
// One streaming pass computing 15 sums per batch reproduces the reference.
//
// Session lessons baked in:
//  R2-R4: never force ILP (launch_bounds min / sched_barrier clusters) — the
//         allocator spills to scratch (WRITE_SIZE 19-190 MB). Rely on TLP.
//  R5:    no device-scope fences / atomic handoff in the hot path (9x).
//  R6:    LDS staging costs more than it saves; unit-stride wasn't the issue —
//         L1 MSHRs already merge the strided triple's line touches.
//  R7:    float3 (dwordx3) per-row loads: 12 B/lane unit stride, every line
//         touched once, every byte consumed, no shuffles/LDS/phases.

__global__ void nn_partial(const float* __restrict__ pred,
                           const float* __restrict__ targ,
                           float* __restrict__ partial) {
    const int bid   = blockIdx.x;
    const int batch = bid >> 4;              // BPB == 16
    const int chunk = bid & 15;
    const long baseRow = (long)batch * N_ROWS + (long)chunk * ROWS_PER_BLOCK;
    const int  tid  = threadIdx.x;

    const float3* __restrict__ p3 =
        reinterpret_cast<const float3*>(pred) + baseRow + tid;
    const float3* __restrict__ t3 =
        reinterpret_cast<const float3*>(targ) + baseRow + tid;

    // acc[0..2]=ra, acc[3..5]=rb, acc[6..14]=mul[c][d]
    float acc[15];
    #pragma unroll
    for (int i = 0; i < 15; ++i) acc[i] = 0.f;

    #pragma unroll 4
    for (int pass = 0; pass < NPASS; ++pass) {
        const float3 p = p3[pass * THREADS];
        const float3 t = t3[pass * THREADS];
        acc[0]  = fmaf(p.x,p.x,acc[0]);  acc[1]  = fmaf(p.y,p.y,acc[1]);  acc[2]  = fmaf(p.z,p.z,acc[2]);
        acc[3]  = fmaf(t.x,t.x,acc[3]);  acc[4]  = fmaf(t.y,t.y,acc[4]);  acc[5]  = fmaf(t.z,t.z,acc[5]);
        acc[6]  = fmaf(p.x,t.x,acc[6]);  acc[7]  = fmaf(p.x,t.y,acc[7]);  acc[8]  = fmaf(p.x,t.z,acc[8]);
        acc[9]  = fmaf(p.y,t.x,acc[9]);  acc[10] = fmaf(p.y,t.y,acc[10]); acc[11] = fmaf(p.y,t.z,acc[11]);
        acc[12] = fmaf(p.z,t.x,acc[12]); acc[13] = fmaf(p.z,t.y,acc[13]); acc[14] = fmaf(p.z,t.z,acc[14]);
    }

    // Wave butterfly reduce (fixed order -> deterministic).
    #pragma unroll
    for (int off = 32; off > 0; off >>= 1) {
        #pragma unroll
        for (int i = 0; i < 15; ++i)
            acc[i] += __shfl_down(acc[i], off, 64);
    }

    __shared__ float wsum[4][15];
    const int wave = tid >> 6;
    const int lane = tid & 63;
    if (lane == 0) {
        #pragma unroll
        for (int i = 0; i < 15; ++i) wsum[wave][i] = acc[i];
    }
    __syncthreads();
    if (tid < 15) {
        partial[(long)bid * 15 + tid] =
            wsum[0][tid] + wsum[1][tid] + wsum[2][tid] + wsum[3][tid];
    }
}

// One block per batch, 64 lanes: lane k < BPB owns one partial vector,
// fixed shfl-tree order -> deterministic.
__global__ void nn_final(const float* __restrict__ partial,
                         float* __restrict__ out) {
    const int b    = blockIdx.x;
    const int lane = threadIdx.x;
    float s[15];
    if (lane < BPB) {
        const float* pp = partial + (long)(b * BPB + lane) * 15;
        #pragma unroll
        for (int i = 0; i < 15; ++i) s[i] = pp[i];
    } else {
        #pragma unroll
        for (int i = 0; i < 15; ++i) s[i] = 0.f;
    }
    #pragma unroll
    for (int off = 8; off > 0; off >>= 1) {
        #pragma unroll
        for (int i = 0; i < 15; ++i)
            s[i] += __shfl_down(s[i], off, 64);
    }
    if (lane == 0) {
        #pragma unroll
        for (int c = 0; c < 3; ++c) {
            float m = 3.0e38f;
            #pragma unroll
            for (int d = 0; d < 3; ++d) {
                float dist = s[c] - 2.0f * s[6 + c * 3 + d] + s[3 + d];
                m = fminf(m, dist);
            }
            out[b * 3 + c] = sqrtf(fmaxf(m, 0.f));
        }
    }
}

extern "C" void kernel_launch(void* const* d_in, const int* in_sizes, int n_in,
                              void* d_out, int out_size, void* d_ws, size_t ws_size,
                              hipStream_t stream) {
    const float* pred = (const float*)d_in[0];
    const float* targ = (const float*)d_in[1];
    float* out     = (float*)d_out;
    float* partial = (float*)d_ws;   // NBATCH*BPB*15 floats = 120 KB << ws

    nn_partial<<<NBATCH * BPB, THREADS, 0, stream>>>(pred, targ, partial);
    nn_final<<<NBATCH, 64, 0, stream>>>(partial, out);
}